// Round 1
// baseline (14.333 us; speedup 1.0000x reference)
//
#include <hip/hip_runtime.h>
#include <math.h>

// ---------------------------------------------------------------------------
// Compile-time PGA Cl(3,0,1) tables.
// Blade basis ordering (matches reference):
//   1, e0, e1, e2, e3, e01, e02, e03, e12, e13, e23, e012, e013, e023, e123, e0123
// Bitmask representation: bit0=e0, bit1=e1, bit2=e2, bit3=e3.
// ---------------------------------------------------------------------------
namespace ct {

constexpr int MASK[16] = {0, 1, 2, 4, 8, 3, 5, 9, 6, 10, 12, 7, 11, 13, 14, 15};
// mask -> basis index
constexpr int IDX[16]  = {0, 1, 2, 5, 3, 6, 8, 11, 4, 7, 9, 12, 10, 13, 14, 15};
constexpr int GRADE[16] = {0, 1, 1, 1, 1, 2, 2, 2, 2, 2, 2, 3, 3, 3, 3, 4};

constexpr int popc(int v) { int c = 0; while (v) { c += v & 1; v >>= 1; } return c; }

// Canonical reordering sign for blade(a) * blade(b), both ascending lists:
// (-1)^(number of inversions between the concatenated lists).
constexpr int rs(int a, int b) {
    int s = 0;
    a >>= 1;
    while (a) { s += popc(a & b); a >>= 1; }
    return (s & 1) ? -1 : 1;
}

struct Tab { int sgn[16][16]; int idx[16][16]; };

// Geometric product table: result blade = a^b; zero iff both contain e0 (e0^2=0);
// e1..e3 square to +1 so only the reordering sign matters.
constexpr Tab make_gp() {
    Tab t{};
    for (int i = 0; i < 16; ++i)
        for (int j = 0; j < 16; ++j) {
            int a = MASK[i], b = MASK[j];
            if (a & b & 1) { t.sgn[i][j] = 0; t.idx[i][j] = 0; }
            else           { t.sgn[i][j] = rs(a, b); t.idx[i][j] = IDX[a ^ b]; }
        }
    return t;
}

// Join table: J = Dinv . wedge(D(x), D(y)).  D = right complement with sorting sign.
// wedge(ca, cb) nonzero iff ca & cb == 0, i.e. a | b == 1111b.
constexpr Tab make_jn() {
    Tab t{};
    for (int i = 0; i < 16; ++i)
        for (int j = 0; j < 16; ++j) {
            int a = MASK[i], b = MASK[j];
            int ca = 15 ^ a, cb = 15 ^ b;
            if (ca & cb) { t.sgn[i][j] = 0; t.idx[i][j] = 0; }
            else {
                int m = ca | cb;      // wedge result (in dual space)
                int p = 15 ^ m;       // undual result blade
                t.sgn[i][j] = rs(a, ca) * rs(b, cb) * rs(ca, cb) * rs(p, m);
                t.idx[i][j] = IDX[p];
            }
        }
    return t;
}

constexpr Tab GP = make_gp();
constexpr Tab JN = make_jn();

} // namespace ct

// ---------------------------------------------------------------------------
// One thread per multivector: 64 B in, 64 B out, ~550 constant-folded FMAs.
// ---------------------------------------------------------------------------
__global__ __launch_bounds__(256) void mvffn_kernel(
    const float* __restrict__ x,
    const float* __restrict__ w1,  const float* __restrict__ v1,  const float* __restrict__ b1,
    const float* __restrict__ w2g, const float* __restrict__ v2g, const float* __restrict__ b2g,
    const float* __restrict__ w2j, const float* __restrict__ v2j, const float* __restrict__ b2j,
    float* __restrict__ out, int n)
{
    const int t = blockIdx.x * blockDim.x + threadIdx.x;
    if (t >= n) return;

    // ---- load one multivector (4 x float4 = 64 B, one full cache line) ----
    const float4* xv = reinterpret_cast<const float4*>(x) + (size_t)t * 4;
    float4 q0 = xv[0], q1 = xv[1], q2 = xv[2], q3 = xv[3];
    float X[16] = { q0.x, q0.y, q0.z, q0.w,  q1.x, q1.y, q1.z, q1.w,
                    q2.x, q2.y, q2.z, q2.w,  q3.x, q3.y, q3.z, q3.w };

    // ---- uniform parameters (L1-cached broadcast loads) ----
    float W1[5], W2G[5], W2J[5], V1[4], V2G[4], V2J[4];
    #pragma unroll
    for (int i = 0; i < 5; ++i) { W1[i] = w1[i]; W2G[i] = w2g[i]; W2J[i] = w2j[i]; }
    #pragma unroll
    for (int i = 0; i < 4; ++i) { V1[i] = v1[i]; V2G[i] = v2g[i]; V2J[i] = v2j[i]; }
    const float B1 = b1[0], B2G = b2g[0], B2J = b2j[0];

    // ---- MVLinear #1: per-grade scale + e0*x branch + scalar bias ----
    float xp[16];
    #pragma unroll
    for (int k = 0; k < 16; ++k) xp[k] = X[k] * W1[ct::GRADE[k]];
    xp[0]  += B1;
    xp[1]  += V1[1] * X[0];                     // e0   <- 1
    xp[5]  += V1[2] * X[2];                     // e01  <- e1
    xp[6]  += V1[2] * X[3];                     // e02  <- e2
    xp[7]  += V1[2] * X[4];                     // e03  <- e3
    xp[11] += V1[3] * X[8];                     // e012 <- e12
    xp[12] += V1[3] * X[9];                     // e013 <- e13
    xp[13] += V1[3] * X[10];                    // e023 <- e23
    // e0123 component of e0*x has grade 4 -> coef2 = 0 (GM[:4]) -> skipped.

    // ---- gated GELU (exact): gate = gelu(scalar part) ----
    const float s0 = xp[0];
    const float gate = 0.5f * s0 * (1.0f + erff(s0 * 0.70710678118654752f));
    float xg[16];
    #pragma unroll
    for (int k = 0; k < 16; ++k) xg[k] = gate * xp[k];

    // ---- bilinear forms: geometric product (192 terms) + join (81 terms) ----
    float gp[16], jn[16];
    #pragma unroll
    for (int k = 0; k < 16; ++k) { gp[k] = 0.0f; jn[k] = 0.0f; }

    #pragma unroll
    for (int i = 0; i < 16; ++i) {
        #pragma unroll
        for (int j = 0; j < 16; ++j) {
            if (ct::GP.sgn[i][j] > 0)      gp[ct::GP.idx[i][j]] += X[i] * xg[j];
            else if (ct::GP.sgn[i][j] < 0) gp[ct::GP.idx[i][j]] -= X[i] * xg[j];
            if (ct::JN.sgn[i][j] > 0)      jn[ct::JN.idx[i][j]] += X[i] * xg[j];
            else if (ct::JN.sgn[i][j] < 0) jn[ct::JN.idx[i][j]] -= X[i] * xg[j];
        }
    }
    // join gated by reference pseudoscalar (reference = x)
    const float ps = X[15];
    #pragma unroll
    for (int k = 0; k < 16; ++k) jn[k] *= ps;

    // ---- MVLinear #2 (gp branch) + MVLinear #3 (join branch), summed ----
    float o[16];
    #pragma unroll
    for (int k = 0; k < 16; ++k)
        o[k] = gp[k] * W2G[ct::GRADE[k]] + jn[k] * W2J[ct::GRADE[k]];
    o[0]  += B2G + B2J;
    o[1]  += V2G[1] * gp[0]  + V2J[1] * jn[0];
    o[5]  += V2G[2] * gp[2]  + V2J[2] * jn[2];
    o[6]  += V2G[2] * gp[3]  + V2J[2] * jn[3];
    o[7]  += V2G[2] * gp[4]  + V2J[2] * jn[4];
    o[11] += V2G[3] * gp[8]  + V2J[3] * jn[8];
    o[12] += V2G[3] * gp[9]  + V2J[3] * jn[9];
    o[13] += V2G[3] * gp[10] + V2J[3] * jn[10];

    // ---- store (4 x float4) ----
    float4* ov = reinterpret_cast<float4*>(out) + (size_t)t * 4;
    ov[0] = make_float4(o[0],  o[1],  o[2],  o[3]);
    ov[1] = make_float4(o[4],  o[5],  o[6],  o[7]);
    ov[2] = make_float4(o[8],  o[9],  o[10], o[11]);
    ov[3] = make_float4(o[12], o[13], o[14], o[15]);
}

extern "C" void kernel_launch(void* const* d_in, const int* in_sizes, int n_in,
                              void* d_out, int out_size, void* d_ws, size_t ws_size,
                              hipStream_t stream) {
    const float* x   = (const float*)d_in[0];
    const float* w1  = (const float*)d_in[1];
    const float* v1  = (const float*)d_in[2];
    const float* b1  = (const float*)d_in[3];
    const float* w2g = (const float*)d_in[4];
    const float* v2g = (const float*)d_in[5];
    const float* b2g = (const float*)d_in[6];
    const float* w2j = (const float*)d_in[7];
    const float* v2j = (const float*)d_in[8];
    const float* b2j = (const float*)d_in[9];
    float* out = (float*)d_out;

    const int n = in_sizes[0] / 16;          // number of multivectors
    const int block = 256;
    const int grid = (n + block - 1) / block;
    mvffn_kernel<<<grid, block, 0, stream>>>(x, w1, v1, b1, w2g, v2g, b2g,
                                             w2j, v2j, b2j, out, n);
}